// Round 5
// baseline (2388.022 us; speedup 1.0000x reference)
//
#include <hip/hip_runtime.h>
#include <hip/hip_bf16.h>

#define T_TOK 8192
#define D_DIM 1024
#define H_DIM 4096
#define E_NUM 8

typedef short bf16x8 __attribute__((ext_vector_type(8)));
typedef float f32x4 __attribute__((ext_vector_type(4)));

__device__ __forceinline__ unsigned short f2bf(float f) {
    union { float f; unsigned int u; } v; v.f = f;
    unsigned int u = v.u;
    u = u + 0x7FFFu + ((u >> 16) & 1u);   // round-to-nearest-even
    return (unsigned short)(u >> 16);
}

__device__ __forceinline__ void gload_lds16(const void* g, void* l) {
    __builtin_amdgcn_global_load_lds(
        (const __attribute__((address_space(1))) unsigned int*)g,
        (__attribute__((address_space(3))) unsigned int*)l,
        16, 0, 0);
}

// XCD-chunked bijective swizzle + 8x4 supertile (T1, m157/m204)
__device__ __forceinline__ void swz_bmbn(int lin, int nbm, int nbn, int& bm, int& bn) {
    const int nwg = nbm * nbn;
    int wgid = ((nwg & 7) == 0) ? ((lin & 7) * (nwg >> 3) + (lin >> 3)) : lin;
    if ((nbm & 7) == 0 && (nbn & 3) == 0) {
        const int per = nbn << 3;
        int stripe = wgid / per;
        int l = wgid - stripe * per;
        int g = l >> 5, r = l & 31;               // 32 = 8 bm x 4 bn
        bm = stripe * 8 + (r >> 2);
        bn = g * 4 + (r & 3);
    } else {
        bm = wgid / nbn;
        bn = wgid - bm * nbn;
    }
}

// ------- gating (fp64, mask-exact) + fused x->bf16 convert -------
__global__ void gate_cvt_kernel(const float* __restrict__ x, const float* __restrict__ Wg,
                                const float* __restrict__ bg, float* __restrict__ wout,
                                unsigned short* __restrict__ xb) {
    int wv = (int)((blockIdx.x * blockDim.x + threadIdx.x) >> 6);  // token id
    int lane = threadIdx.x & 63;
    if (wv >= T_TOK) return;
    const float* xr = x + (size_t)wv * D_DIM;
    unsigned short* xo = xb + (size_t)wv * D_DIM;
    double acc[E_NUM] = {0, 0, 0, 0, 0, 0, 0, 0};
    for (int i = 0; i < D_DIM / 64; ++i) {
        int d = i * 64 + lane;
        float xf = xr[d];
        xo[d] = f2bf(xf);
        double xv = (double)xf;
        const float* wr = Wg + (size_t)d * E_NUM;
        #pragma unroll
        for (int e = 0; e < E_NUM; ++e) acc[e] += xv * (double)wr[e];
    }
    #pragma unroll
    for (int e = 0; e < E_NUM; ++e) {
        double v = acc[e];
        for (int s = 32; s; s >>= 1) v += __shfl_down(v, s, 64);
        acc[e] = v;
    }
    if (lane == 0) {
        #pragma unroll
        for (int e = 0; e < E_NUM; ++e) {
            double z = acc[e] + (double)bg[e];
            float p = (float)(1.0 / (1.0 + exp(-z)));
            wout[(size_t)wv * E_NUM + e] = (p > 0.5f) ? p : 0.0f;
        }
    }
}

// ------- per-expert transpose+convert: in[e][R][C] fp32 -> out[e][C][R] bf16 -------
__global__ void transpose_cvt(const float* __restrict__ in, unsigned short* __restrict__ out,
                              int R, int C) {
    __shared__ unsigned short tile[64][65];
    int e = blockIdx.z;
    const float* src = in + (size_t)e * R * C;
    unsigned short* dst = out + (size_t)e * R * C;
    int c0 = blockIdx.x * 64, r0 = blockIdx.y * 64;
    int t = threadIdx.x;
    int cc = (t & 15) * 4;
    int rr = t >> 4;
    #pragma unroll
    for (int p = 0; p < 4; ++p) {
        int r = rr + p * 16;
        float4 v = *(const float4*)(src + (size_t)(r0 + r) * C + c0 + cc);
        tile[cc + 0][r] = f2bf(v.x);
        tile[cc + 1][r] = f2bf(v.y);
        tile[cc + 2][r] = f2bf(v.z);
        tile[cc + 3][r] = f2bf(v.w);
    }
    __syncthreads();
    int rr4 = (t & 15) * 4;
    int cw = t >> 4;
    #pragma unroll
    for (int p = 0; p < 4; ++p) {
        int c = cw + p * 16;
        ushort4 o;
        o.x = tile[c][rr4 + 0];
        o.y = tile[c][rr4 + 1];
        o.z = tile[c][rr4 + 2];
        o.w = tile[c][rr4 + 3];
        *(ushort4*)(dst + (size_t)(c0 + c) * R + r0 + rr4) = o;
    }
}

// ---------------- sentinel: workspace too small marker ----------------
__global__ void sentinel_kernel(float* out, size_t n) {
    size_t i = (size_t)blockIdx.x * blockDim.x + threadIdx.x;
    size_t st = (size_t)gridDim.x * blockDim.x;
    for (; i < n; i += st) out[i] = 12345.0f;
}

// ============ GEMM1 (all experts, one dispatch): Hc[e] = w.*relu(Xb @ W1T[e]^T + b1[e]) ============
// A = Xb chunk base [cs][D], B = W1T[e] [H][D]; e = e0 + blockIdx.y.
// Hc[e*hstride + r*H + cn] = bf16( relu(acc + b1[e][cn]) * wgt[t0+r][e] )
__global__ __launch_bounds__(256) void gemm1_all(
    const unsigned short* __restrict__ A,
    const unsigned short* __restrict__ W1T,
    unsigned short* __restrict__ Hc,
    const float* __restrict__ b1,
    const float* __restrict__ wgt,
    int t0, int e0, size_t hstride, int nbm)
{
    __shared__ __align__(16) unsigned short lA[128 * 32];
    __shared__ __align__(16) unsigned short lB[128 * 32];
    const int e = e0 + blockIdx.y;
    const int nbn = H_DIM / 128;
    int bm, bn;
    swz_bmbn(blockIdx.x, nbm, nbn, bm, bn);

    const unsigned short* B = W1T + (size_t)e * D_DIM * H_DIM;
    unsigned short* Ho = Hc + (size_t)e * hstride;

    const int tid = threadIdx.x;
    const int lane = tid & 63, wid = tid >> 6;
    const int wr = wid >> 1, wc = wid & 1;
    const int fr = lane & 15, fq = lane >> 4;
    const int srow = tid >> 2;
    const int sk = (tid & 3) * 8;

    const unsigned short* A0 = A + (size_t)(bm * 128 + srow) * D_DIM + sk;
    const unsigned short* A1 = A0 + (size_t)64 * D_DIM;
    const unsigned short* B0 = B + (size_t)(bn * 128 + srow) * D_DIM + sk;
    const unsigned short* B1 = B0 + (size_t)64 * D_DIM;

    unsigned short* lA0 = lA + wid * 512;
    unsigned short* lA1 = lA + 2048 + wid * 512;
    unsigned short* lB0 = lB + wid * 512;
    unsigned short* lB1 = lB + 2048 + wid * 512;

    f32x4 acc[4][4];
    #pragma unroll
    for (int m = 0; m < 4; ++m)
        #pragma unroll
        for (int n = 0; n < 4; ++n)
            acc[m][n] = (f32x4){0.f, 0.f, 0.f, 0.f};

    for (int k0 = 0; k0 < D_DIM; k0 += 32) {
        __syncthreads();
        gload_lds16(A0 + k0, lA0);
        gload_lds16(A1 + k0, lA1);
        gload_lds16(B0 + k0, lB0);
        gload_lds16(B1 + k0, lB1);
        __syncthreads();
        bf16x8 af[4], bfr[4];
        #pragma unroll
        for (int m = 0; m < 4; ++m)
            af[m] = *(const bf16x8*)(lA + ((wr * 64 + m * 16 + fr) * 32 + fq * 8));
        #pragma unroll
        for (int n = 0; n < 4; ++n)
            bfr[n] = *(const bf16x8*)(lB + ((wc * 64 + n * 16 + fr) * 32 + fq * 8));
        #pragma unroll
        for (int m = 0; m < 4; ++m)
            #pragma unroll
            for (int n = 0; n < 4; ++n)
                acc[m][n] = __builtin_amdgcn_mfma_f32_16x16x32_bf16(af[m], bfr[n], acc[m][n], 0, 0, 0);
    }

    #pragma unroll
    for (int m = 0; m < 4; ++m) {
        const int rbase = bm * 128 + wr * 64 + m * 16 + fq * 4;
        #pragma unroll
        for (int n = 0; n < 4; ++n) {
            const int cn = bn * 128 + wc * 64 + n * 16 + fr;
            const float bb = b1[(size_t)e * H_DIM + cn];
            #pragma unroll
            for (int j = 0; j < 4; ++j) {
                const int r = rbase + j;
                const float w = wgt[(size_t)(t0 + r) * E_NUM + e];
                float v = fmaxf(acc[m][n][j] + bb, 0.0f) * w;
                Ho[(size_t)r * H_DIM + cn] = f2bf(v);
            }
        }
    }
}

// ============ GEMM2 fused over experts: out = sum_e (w.*h_e) @ W2T[e]^T + (W @ b2) ============
// Hc already pre-scaled by w. acc = sum_e Hc[e] @ W2T[e]^T; epilogue adds sum_e w[t,e]*b2[e][cn].
__global__ __launch_bounds__(256) void gemm2_fused(
    const unsigned short* __restrict__ Hc,
    const unsigned short* __restrict__ W2T,
    float* __restrict__ out,
    const float* __restrict__ b2,
    const float* __restrict__ wgt,
    int t0, size_t hstride, int nbm)
{
    __shared__ __align__(16) unsigned short lA[128 * 32];
    __shared__ __align__(16) unsigned short lB[128 * 32];
    const int nbn = D_DIM / 128;
    int bm, bn;
    swz_bmbn(blockIdx.x, nbm, nbn, bm, bn);

    const int tid = threadIdx.x;
    const int lane = tid & 63, wid = tid >> 6;
    const int wr = wid >> 1, wc = wid & 1;
    const int fr = lane & 15, fq = lane >> 4;
    const int srow = tid >> 2;
    const int sk = (tid & 3) * 8;

    unsigned short* lA0 = lA + wid * 512;
    unsigned short* lA1 = lA + 2048 + wid * 512;
    unsigned short* lB0 = lB + wid * 512;
    unsigned short* lB1 = lB + 2048 + wid * 512;

    f32x4 acc[4][4];
    #pragma unroll
    for (int m = 0; m < 4; ++m)
        #pragma unroll
        for (int n = 0; n < 4; ++n)
            acc[m][n] = (f32x4){0.f, 0.f, 0.f, 0.f};

    for (int e = 0; e < E_NUM; ++e) {
        const unsigned short* A0 = Hc + (size_t)e * hstride
                                 + (size_t)(bm * 128 + srow) * H_DIM + sk;
        const unsigned short* A1 = A0 + (size_t)64 * H_DIM;
        const unsigned short* B0 = W2T + (size_t)e * D_DIM * H_DIM
                                 + (size_t)(bn * 128 + srow) * H_DIM + sk;
        const unsigned short* B1 = B0 + (size_t)64 * H_DIM;
        for (int k0 = 0; k0 < H_DIM; k0 += 32) {
            __syncthreads();
            gload_lds16(A0 + k0, lA0);
            gload_lds16(A1 + k0, lA1);
            gload_lds16(B0 + k0, lB0);
            gload_lds16(B1 + k0, lB1);
            __syncthreads();
            bf16x8 af[4], bfr[4];
            #pragma unroll
            for (int m = 0; m < 4; ++m)
                af[m] = *(const bf16x8*)(lA + ((wr * 64 + m * 16 + fr) * 32 + fq * 8));
            #pragma unroll
            for (int n = 0; n < 4; ++n)
                bfr[n] = *(const bf16x8*)(lB + ((wc * 64 + n * 16 + fr) * 32 + fq * 8));
            #pragma unroll
            for (int m = 0; m < 4; ++m)
                #pragma unroll
                for (int n = 0; n < 4; ++n)
                    acc[m][n] = __builtin_amdgcn_mfma_f32_16x16x32_bf16(af[m], bfr[n], acc[m][n], 0, 0, 0);
        }
    }

    #pragma unroll
    for (int m = 0; m < 4; ++m) {
        const int rbase = bm * 128 + wr * 64 + m * 16 + fq * 4;
        #pragma unroll
        for (int n = 0; n < 4; ++n) {
            const int cn = bn * 128 + wc * 64 + n * 16 + fr;
            float b2v[E_NUM];
            #pragma unroll
            for (int e = 0; e < E_NUM; ++e) b2v[e] = b2[(size_t)e * D_DIM + cn];
            #pragma unroll
            for (int j = 0; j < 4; ++j) {
                const int row = t0 + rbase + j;
                const float* w8 = wgt + (size_t)row * E_NUM;
                float v = acc[m][n][j];
                #pragma unroll
                for (int e = 0; e < E_NUM; ++e) v += w8[e] * b2v[e];
                out[(size_t)row * D_DIM + cn] = v;
            }
        }
    }
}

// ---------- fallback per-expert gemm2 (Hc pre-scaled): MODE 1 store / MODE 2 accumulate ----------
template<int MODE>
__global__ __launch_bounds__(256) void gemm2_sep(
    const unsigned short* __restrict__ A,
    const unsigned short* __restrict__ B,
    float* __restrict__ out,
    const float* __restrict__ bias,
    const float* __restrict__ wts,
    int t0, int e, int nbm)
{
    __shared__ __align__(16) unsigned short lA[128 * 32];
    __shared__ __align__(16) unsigned short lB[128 * 32];
    const int nbn = D_DIM / 128;
    int bm, bn;
    swz_bmbn(blockIdx.x, nbm, nbn, bm, bn);

    const int tid = threadIdx.x;
    const int lane = tid & 63, wid = tid >> 6;
    const int wr = wid >> 1, wc = wid & 1;
    const int fr = lane & 15, fq = lane >> 4;
    const int srow = tid >> 2;
    const int sk = (tid & 3) * 8;

    const unsigned short* A0 = A + (size_t)(bm * 128 + srow) * H_DIM + sk;
    const unsigned short* A1 = A0 + (size_t)64 * H_DIM;
    const unsigned short* B0 = B + (size_t)(bn * 128 + srow) * H_DIM + sk;
    const unsigned short* B1 = B0 + (size_t)64 * H_DIM;

    unsigned short* lA0 = lA + wid * 512;
    unsigned short* lA1 = lA + 2048 + wid * 512;
    unsigned short* lB0 = lB + wid * 512;
    unsigned short* lB1 = lB + 2048 + wid * 512;

    f32x4 acc[4][4];
    #pragma unroll
    for (int m = 0; m < 4; ++m)
        #pragma unroll
        for (int n = 0; n < 4; ++n)
            acc[m][n] = (f32x4){0.f, 0.f, 0.f, 0.f};

    for (int k0 = 0; k0 < H_DIM; k0 += 32) {
        __syncthreads();
        gload_lds16(A0 + k0, lA0);
        gload_lds16(A1 + k0, lA1);
        gload_lds16(B0 + k0, lB0);
        gload_lds16(B1 + k0, lB1);
        __syncthreads();
        bf16x8 af[4], bfr[4];
        #pragma unroll
        for (int m = 0; m < 4; ++m)
            af[m] = *(const bf16x8*)(lA + ((wr * 64 + m * 16 + fr) * 32 + fq * 8));
        #pragma unroll
        for (int n = 0; n < 4; ++n)
            bfr[n] = *(const bf16x8*)(lB + ((wc * 64 + n * 16 + fr) * 32 + fq * 8));
        #pragma unroll
        for (int m = 0; m < 4; ++m)
            #pragma unroll
            for (int n = 0; n < 4; ++n)
                acc[m][n] = __builtin_amdgcn_mfma_f32_16x16x32_bf16(af[m], bfr[n], acc[m][n], 0, 0, 0);
    }

    #pragma unroll
    for (int m = 0; m < 4; ++m) {
        const int rbase = bm * 128 + wr * 64 + m * 16 + fq * 4;
        #pragma unroll
        for (int n = 0; n < 4; ++n) {
            const int cn = bn * 128 + wc * 64 + n * 16 + fr;
            const float bb = bias[cn];
            #pragma unroll
            for (int j = 0; j < 4; ++j) {
                const int row = t0 + rbase + j;
                const float w = wts[(size_t)row * E_NUM + e];
                const float v = acc[m][n][j] + w * bb;   // Hc pre-scaled: only bias needs w
                float* p = out + (size_t)row * D_DIM + cn;
                if (MODE == 1) *p = v;
                else *p += v;
            }
        }
    }
}

extern "C" void kernel_launch(void* const* d_in, const int* in_sizes, int n_in,
                              void* d_out, int out_size, void* d_ws, size_t ws_size,
                              hipStream_t stream) {
    const float* x  = (const float*)d_in[0];
    const float* Wg = (const float*)d_in[1];
    const float* bg = (const float*)d_in[2];
    const float* W1 = (const float*)d_in[3];
    const float* b1 = (const float*)d_in[4];
    const float* W2 = (const float*)d_in[5];
    const float* b2 = (const float*)d_in[6];
    float* out = (float*)d_out;
    char* ws = (char*)d_ws;

    const size_t off_w  = 0;                                          // gate weights: 256 KiB
    const size_t off_x  = 262144;                                     // Xbf16: 16 MiB
    const size_t off_w1 = off_x + (size_t)T_TOK * D_DIM * 2;          // W1T bf16 [E][H][D]: 64 MiB
    const size_t off_w2 = off_w1 + (size_t)E_NUM * D_DIM * H_DIM * 2; // W2T bf16 [E][D][H]: 64 MiB
    const size_t off_h  = off_w2 + (size_t)E_NUM * D_DIM * H_DIM * 2; // Hc bf16
    const size_t min_h  = (size_t)128 * H_DIM * 2;

    if (ws_size < off_h + min_h) {
        sentinel_kernel<<<2048, 256, 0, stream>>>(out, (size_t)T_TOK * D_DIM);
        return;
    }
    size_t avail = ws_size - off_h;

    float* wgt = (float*)(ws + off_w);
    unsigned short* Xb  = (unsigned short*)(ws + off_x);
    unsigned short* W1T = (unsigned short*)(ws + off_w1);
    unsigned short* W2T = (unsigned short*)(ws + off_w2);
    unsigned short* Hc  = (unsigned short*)(ws + off_h);

    gate_cvt_kernel<<<T_TOK / 4, 256, 0, stream>>>(x, Wg, bg, wgt, Xb);
    transpose_cvt<<<dim3(H_DIM / 64, D_DIM / 64, E_NUM), 256, 0, stream>>>(W1, W1T, D_DIM, H_DIM);
    transpose_cvt<<<dim3(D_DIM / 64, H_DIM / 64, E_NUM), 256, 0, stream>>>(W2, W2T, H_DIM, D_DIM);

    // fused path: Hc holds all 8 experts for a TC-token chunk
    size_t tcf = avail / ((size_t)E_NUM * H_DIM * 2);
    tcf = (tcf / 128) * 128;
    if (tcf > T_TOK) tcf = T_TOK;

    if (tcf >= 128) {
        const int TC = (int)tcf;
        const size_t hstride = (size_t)TC * H_DIM;
        for (int t0 = 0; t0 < T_TOK; t0 += TC) {
            int cs = (T_TOK - t0 < TC) ? (T_TOK - t0) : TC;
            const int nbm = cs / 128;
            gemm1_all<<<dim3(nbm * (H_DIM / 128), E_NUM), 256, 0, stream>>>(
                Xb + (size_t)t0 * D_DIM, W1T, Hc, b1, wgt, t0, 0, hstride, nbm);
            gemm2_fused<<<nbm * (D_DIM / 128), 256, 0, stream>>>(
                Hc, W2T, out, b2, wgt, t0, hstride, nbm);
        }
    } else {
        // fallback: one expert at a time in Hc
        size_t tc = avail / ((size_t)H_DIM * 2);
        tc = (tc / 128) * 128;
        if (tc > T_TOK) tc = T_TOK;
        const int TC = (int)tc;
        for (int t0 = 0; t0 < T_TOK; t0 += TC) {
            int cs = (T_TOK - t0 < TC) ? (T_TOK - t0) : TC;
            const int nbm = cs / 128;
            for (int e = 0; e < E_NUM; ++e) {
                gemm1_all<<<dim3(nbm * (H_DIM / 128), 1), 256, 0, stream>>>(
                    Xb + (size_t)t0 * D_DIM, W1T, Hc, b1, wgt, t0, e, 0, nbm);
                if (e == 0)
                    gemm2_sep<1><<<nbm * (D_DIM / 128), 256, 0, stream>>>(
                        Hc, W2T + (size_t)e * D_DIM * H_DIM, out,
                        b2 + (size_t)e * D_DIM, wgt, t0, e, nbm);
                else
                    gemm2_sep<2><<<nbm * (D_DIM / 128), 256, 0, stream>>>(
                        Hc, W2T + (size_t)e * D_DIM * H_DIM, out,
                        b2 + (size_t)e * D_DIM, wgt, t0, e, nbm);
            }
        }
    }
}

// Round 6
// 1598.757 us; speedup vs baseline: 1.4937x; 1.4937x over previous
//
#include <hip/hip_runtime.h>
#include <hip/hip_bf16.h>

#define T_TOK 8192
#define D_DIM 1024
#define H_DIM 4096
#define E_NUM 8

typedef short bf16x8 __attribute__((ext_vector_type(8)));
typedef float f32x4 __attribute__((ext_vector_type(4)));

__device__ __forceinline__ unsigned short f2bf(float f) {
    union { float f; unsigned int u; } v; v.f = f;
    unsigned int u = v.u;
    u = u + 0x7FFFu + ((u >> 16) & 1u);   // round-to-nearest-even
    return (unsigned short)(u >> 16);
}

__device__ __forceinline__ void gload_lds16(const void* g, void* l) {
    __builtin_amdgcn_global_load_lds(
        (const __attribute__((address_space(1))) unsigned int*)g,
        (__attribute__((address_space(3))) unsigned int*)l,
        16, 0, 0);
}

// phase fences (rule 18 + pinned raw barrier)
#define SBAR() { __builtin_amdgcn_sched_barrier(0); __builtin_amdgcn_s_barrier(); __builtin_amdgcn_sched_barrier(0); }
#define LGKM0() { asm volatile("s_waitcnt lgkmcnt(0)" ::: "memory"); __builtin_amdgcn_sched_barrier(0); }
#define VMC4() { asm volatile("s_waitcnt vmcnt(4)" ::: "memory"); __builtin_amdgcn_sched_barrier(0); }
#define VMC0() { asm volatile("s_waitcnt vmcnt(0)" ::: "memory"); __builtin_amdgcn_sched_barrier(0); }

// XCD-chunked bijective swizzle + 8x4 supertile (T1, m157/m204)
__device__ __forceinline__ void swz_bmbn(int lin, int nbm, int nbn, int& bm, int& bn) {
    const int nwg = nbm * nbn;
    int wgid = ((nwg & 7) == 0) ? ((lin & 7) * (nwg >> 3) + (lin >> 3)) : lin;
    if ((nbm & 7) == 0 && (nbn & 3) == 0) {
        const int per = nbn << 3;
        int stripe = wgid / per;
        int l = wgid - stripe * per;
        int g = l >> 5, r = l & 31;               // 32 = 8 bm x 4 bn
        bm = stripe * 8 + (r >> 2);
        bn = g * 4 + (r & 3);
    } else {
        bm = wgid / nbn;
        bn = wgid - bm * nbn;
    }
}

// ------- gating (fp64, mask-exact) + fused x->bf16 convert -------
__global__ void gate_cvt_kernel(const float* __restrict__ x, const float* __restrict__ Wg,
                                const float* __restrict__ bg, float* __restrict__ wout,
                                unsigned short* __restrict__ xb) {
    int wv = (int)((blockIdx.x * blockDim.x + threadIdx.x) >> 6);  // token id
    int lane = threadIdx.x & 63;
    if (wv >= T_TOK) return;
    const float* xr = x + (size_t)wv * D_DIM;
    unsigned short* xo = xb + (size_t)wv * D_DIM;
    double acc[E_NUM] = {0, 0, 0, 0, 0, 0, 0, 0};
    for (int i = 0; i < D_DIM / 64; ++i) {
        int d = i * 64 + lane;
        float xf = xr[d];
        xo[d] = f2bf(xf);
        double xv = (double)xf;
        const float* wr = Wg + (size_t)d * E_NUM;
        #pragma unroll
        for (int e = 0; e < E_NUM; ++e) acc[e] += xv * (double)wr[e];
    }
    #pragma unroll
    for (int e = 0; e < E_NUM; ++e) {
        double v = acc[e];
        for (int s = 32; s; s >>= 1) v += __shfl_down(v, s, 64);
        acc[e] = v;
    }
    if (lane == 0) {
        #pragma unroll
        for (int e = 0; e < E_NUM; ++e) {
            double z = acc[e] + (double)bg[e];
            float p = (float)(1.0 / (1.0 + exp(-z)));
            wout[(size_t)wv * E_NUM + e] = (p > 0.5f) ? p : 0.0f;
        }
    }
}

// ------- per-expert transpose+convert: in[e][R][C] fp32 -> out[e][C][R] bf16 -------
__global__ void transpose_cvt(const float* __restrict__ in, unsigned short* __restrict__ out,
                              int R, int C) {
    __shared__ unsigned short tile[64][65];
    int e = blockIdx.z;
    const float* src = in + (size_t)e * R * C;
    unsigned short* dst = out + (size_t)e * R * C;
    int c0 = blockIdx.x * 64, r0 = blockIdx.y * 64;
    int t = threadIdx.x;
    int cc = (t & 15) * 4;
    int rr = t >> 4;
    #pragma unroll
    for (int p = 0; p < 4; ++p) {
        int r = rr + p * 16;
        float4 v = *(const float4*)(src + (size_t)(r0 + r) * C + c0 + cc);
        tile[cc + 0][r] = f2bf(v.x);
        tile[cc + 1][r] = f2bf(v.y);
        tile[cc + 2][r] = f2bf(v.z);
        tile[cc + 3][r] = f2bf(v.w);
    }
    __syncthreads();
    int rr4 = (t & 15) * 4;
    int cw = t >> 4;
    #pragma unroll
    for (int p = 0; p < 4; ++p) {
        int c = cw + p * 16;
        ushort4 o;
        o.x = tile[c][rr4 + 0];
        o.y = tile[c][rr4 + 1];
        o.z = tile[c][rr4 + 2];
        o.w = tile[c][rr4 + 3];
        *(ushort4*)(dst + (size_t)(c0 + c) * R + r0 + rr4) = o;
    }
}

// ---------------- sentinel: workspace too small marker ----------------
__global__ void sentinel_kernel(float* out, size_t n) {
    size_t i = (size_t)blockIdx.x * blockDim.x + threadIdx.x;
    size_t st = (size_t)gridDim.x * blockDim.x;
    for (; i < n; i += st) out[i] = 12345.0f;
}

// =================== GEMM1, 256x256 tile, BK=64, 8-wave, 4-phase/K-tile ===================
// C[cs, H] tile: Hc[r][cn] = bf16( relu(Xb@W1T[e]^T + b1[e]) * wgt[t0+r][e] )
// A = Xb chunk [cs][1024], B = W1T[e] [4096][1024]. NT = 1024/64 = 16 K-tiles.
// LDS: 2 buffers x (A 256x64 + B 256x64) bf16 = 128 KiB. XOR swizzle: c16 ^= (row&7),
// applied to pre-swizzled GLOBAL source (gload_lds dest stays linear) and to ds_read addr.
__global__ __launch_bounds__(512, 2) void gemm1_8ph(
    const unsigned short* __restrict__ A,
    const unsigned short* __restrict__ W1T,
    unsigned short* __restrict__ Hc,
    const float* __restrict__ b1,
    const float* __restrict__ wgt,
    int t0, int e, int nbm)
{
    __shared__ __align__(16) unsigned short lA[2][16384];
    __shared__ __align__(16) unsigned short lB[2][16384];

    const int nbn = H_DIM / 256;   // 16
    int bm, bn;
    swz_bmbn(blockIdx.x, nbm, nbn, bm, bn);

    const int tid = threadIdx.x;
    const int lane = tid & 63, wid = tid >> 6;
    const int wr = wid >> 2;        // 0..1  (M half)
    const int wcn = wid & 3;        // 0..3  (N quarter)
    const int fr = lane & 15, fq = lane >> 4;

    // staging per-thread constants: row srow within half-issue, col granule pre-swizzled
    const int srow = tid >> 3;                                    // 0..63
    const int scol = (((tid & 7) ^ (srow & 7)) << 3);             // element offset
    const unsigned short* Ab = A + (size_t)(bm * 256 + srow) * D_DIM + scol;
    const unsigned short* Bb = W1T + (size_t)e * H_DIM * D_DIM
                             + (size_t)(bn * 256 + srow) * D_DIM + scol;

    // ds_read slot constants: slot(kk) = (kk*4 + fq) ^ (fr&7)
    const int s0 = ((0 << 2) | fq) ^ (fr & 7);
    const int s1 = ((1 << 2) | fq) ^ (fr & 7);

    f32x4 acc[8][4];
    #pragma unroll
    for (int m = 0; m < 8; ++m)
        #pragma unroll
        for (int n = 0; n < 4; ++n)
            acc[m][n] = (f32x4){0.f, 0.f, 0.f, 0.f};

    bf16x8 a[4][2], b[4][2];

    // stage one half-tile (2 x gload_lds, 8 KiB each): hf = 0/1 (rows 0-127 / 128-255)
    auto stageA = [&](int bf, int hf, int kt) {
        const unsigned short* s = Ab + (size_t)(hf * 128) * D_DIM + kt * 64;
        gload_lds16(s,                     &lA[bf][hf * 8192 + tid * 8]);
        gload_lds16(s + (size_t)64 * D_DIM, &lA[bf][hf * 8192 + 4096 + tid * 8]);
    };
    auto stageB = [&](int bf, int hf, int kt) {
        const unsigned short* s = Bb + (size_t)(hf * 128) * D_DIM + kt * 64;
        gload_lds16(s,                     &lB[bf][hf * 8192 + tid * 8]);
        gload_lds16(s + (size_t)64 * D_DIM, &lB[bf][hf * 8192 + 4096 + tid * 8]);
    };

    // prologue: B0(0),A0(0),A1(0),B1(0),B0(1),A0(1)  (order matters for vmcnt counting)
    stageB(0, 0, 0);
    stageA(0, 0, 0);
    stageA(0, 1, 0);
    stageB(0, 1, 0);
    stageB(1, 0, 1);
    stageA(1, 0, 1);
    VMC4();
    SBAR();

    int cur = 0;
    for (int t = 0; t < 16; ++t) {
        const int nxt = cur ^ 1;
        // ---- ph0: read A[mh0]+B[nh0]; stage A1(t+1); MFMA (mh0,nh0) ----
        #pragma unroll
        for (int mm = 0; mm < 4; ++mm) {
            const int r = wr * 128 + mm * 16 + fr;
            a[mm][0] = *(const bf16x8*)&lA[cur][r * 64 + s0 * 8];
            a[mm][1] = *(const bf16x8*)&lA[cur][r * 64 + s1 * 8];
        }
        #pragma unroll
        for (int n = 0; n < 2; ++n) {
            const int r = wcn * 64 + n * 16 + fr;
            b[n][0] = *(const bf16x8*)&lB[cur][r * 64 + s0 * 8];
            b[n][1] = *(const bf16x8*)&lB[cur][r * 64 + s1 * 8];
        }
        if (t + 1 < 16) stageA(nxt, 1, t + 1);
        SBAR(); LGKM0();
        __builtin_amdgcn_s_setprio(1);
        #pragma unroll
        for (int kk = 0; kk < 2; ++kk)
            #pragma unroll
            for (int mm = 0; mm < 4; ++mm) {
                acc[mm][0] = __builtin_amdgcn_mfma_f32_16x16x32_bf16(a[mm][kk], b[0][kk], acc[mm][0], 0, 0, 0);
                acc[mm][1] = __builtin_amdgcn_mfma_f32_16x16x32_bf16(a[mm][kk], b[1][kk], acc[mm][1], 0, 0, 0);
            }
        __builtin_amdgcn_s_setprio(0);
        SBAR();
        // ---- ph1: read B[nh1]; stage B1(t+1); MFMA (mh0,nh1) ----
        #pragma unroll
        for (int n = 2; n < 4; ++n) {
            const int r = wcn * 64 + n * 16 + fr;
            b[n][0] = *(const bf16x8*)&lB[cur][r * 64 + s0 * 8];
            b[n][1] = *(const bf16x8*)&lB[cur][r * 64 + s1 * 8];
        }
        if (t + 1 < 16) stageB(nxt, 1, t + 1);
        SBAR(); LGKM0();
        __builtin_amdgcn_s_setprio(1);
        #pragma unroll
        for (int kk = 0; kk < 2; ++kk)
            #pragma unroll
            for (int mm = 0; mm < 4; ++mm) {
                acc[mm][2] = __builtin_amdgcn_mfma_f32_16x16x32_bf16(a[mm][kk], b[2][kk], acc[mm][2], 0, 0, 0);
                acc[mm][3] = __builtin_amdgcn_mfma_f32_16x16x32_bf16(a[mm][kk], b[3][kk], acc[mm][3], 0, 0, 0);
            }
        __builtin_amdgcn_s_setprio(0);
        SBAR();
        // ---- ph2: read A[mh1]; stage B0(t+2) into cur (B halves read-dead after ph1); MFMA (mh1,nh0) ----
        #pragma unroll
        for (int mm = 0; mm < 4; ++mm) {
            const int r = wr * 128 + (mm + 4) * 16 + fr;
            a[mm][0] = *(const bf16x8*)&lA[cur][r * 64 + s0 * 8];
            a[mm][1] = *(const bf16x8*)&lA[cur][r * 64 + s1 * 8];
        }
        if (t + 2 < 16) stageB(cur, 0, t + 2);
        SBAR(); LGKM0();
        __builtin_amdgcn_s_setprio(1);
        #pragma unroll
        for (int kk = 0; kk < 2; ++kk)
            #pragma unroll
            for (int mm = 0; mm < 4; ++mm) {
                acc[mm + 4][0] = __builtin_amdgcn_mfma_f32_16x16x32_bf16(a[mm][kk], b[0][kk], acc[mm + 4][0], 0, 0, 0);
                acc[mm + 4][1] = __builtin_amdgcn_mfma_f32_16x16x32_bf16(a[mm][kk], b[1][kk], acc[mm + 4][1], 0, 0, 0);
            }
        __builtin_amdgcn_s_setprio(0);
        SBAR();
        // ---- ph3: stage A0(t+2) into cur (A halves read-dead after ph2); counted vmcnt; MFMA (mh1,nh1) ----
        if (t + 2 < 16) stageA(cur, 0, t + 2);
        if (t < 14) { VMC4(); } else { VMC0(); }
        SBAR(); LGKM0();
        __builtin_amdgcn_s_setprio(1);
        #pragma unroll
        for (int kk = 0; kk < 2; ++kk)
            #pragma unroll
            for (int mm = 0; mm < 4; ++mm) {
                acc[mm + 4][2] = __builtin_amdgcn_mfma_f32_16x16x32_bf16(a[mm][kk], b[2][kk], acc[mm + 4][2], 0, 0, 0);
                acc[mm + 4][3] = __builtin_amdgcn_mfma_f32_16x16x32_bf16(a[mm][kk], b[3][kk], acc[mm + 4][3], 0, 0, 0);
            }
        __builtin_amdgcn_s_setprio(0);
        SBAR();
        cur = nxt;
    }

    // epilogue: relu(acc+b1)*w -> bf16 Hc (chunk-local rows)
    #pragma unroll
    for (int m = 0; m < 8; ++m) {
        const int rbase = bm * 256 + wr * 128 + m * 16 + fq * 4;
        #pragma unroll
        for (int n = 0; n < 4; ++n) {
            const int cn = bn * 256 + wcn * 64 + n * 16 + fr;
            const float bb = b1[(size_t)e * H_DIM + cn];
            #pragma unroll
            for (int j = 0; j < 4; ++j) {
                const int r = rbase + j;
                const float w = wgt[(size_t)(t0 + r) * E_NUM + e];
                float v = fmaxf(acc[m][n][j] + bb, 0.0f) * w;
                Hc[(size_t)r * H_DIM + cn] = f2bf(v);
            }
        }
    }
}

// ---------- per-expert gemm2 (m97 128^2, Hc pre-scaled): MODE 1 store / MODE 2 accumulate ----------
template<int MODE>
__global__ __launch_bounds__(256) void gemm2_sep(
    const unsigned short* __restrict__ A,
    const unsigned short* __restrict__ B,
    float* __restrict__ out,
    const float* __restrict__ bias,
    const float* __restrict__ wts,
    int t0, int e, int nbm)
{
    __shared__ __align__(16) unsigned short lA[128 * 32];
    __shared__ __align__(16) unsigned short lB[128 * 32];
    const int nbn = D_DIM / 128;
    int bm, bn;
    swz_bmbn(blockIdx.x, nbm, nbn, bm, bn);

    const int tid = threadIdx.x;
    const int lane = tid & 63, wid = tid >> 6;
    const int wr = wid >> 1, wc = wid & 1;
    const int fr = lane & 15, fq = lane >> 4;
    const int srow = tid >> 2;
    const int sk = (tid & 3) * 8;

    const unsigned short* A0 = A + (size_t)(bm * 128 + srow) * H_DIM + sk;
    const unsigned short* A1 = A0 + (size_t)64 * H_DIM;
    const unsigned short* B0 = B + (size_t)(bn * 128 + srow) * H_DIM + sk;
    const unsigned short* B1 = B0 + (size_t)64 * H_DIM;

    unsigned short* lA0 = lA + wid * 512;
    unsigned short* lA1 = lA + 2048 + wid * 512;
    unsigned short* lB0 = lB + wid * 512;
    unsigned short* lB1 = lB + 2048 + wid * 512;

    f32x4 acc[4][4];
    #pragma unroll
    for (int m = 0; m < 4; ++m)
        #pragma unroll
        for (int n = 0; n < 4; ++n)
            acc[m][n] = (f32x4){0.f, 0.f, 0.f, 0.f};

    for (int k0 = 0; k0 < H_DIM; k0 += 32) {
        __syncthreads();
        gload_lds16(A0 + k0, lA0);
        gload_lds16(A1 + k0, lA1);
        gload_lds16(B0 + k0, lB0);
        gload_lds16(B1 + k0, lB1);
        __syncthreads();
        bf16x8 af[4], bfr[4];
        #pragma unroll
        for (int m = 0; m < 4; ++m)
            af[m] = *(const bf16x8*)(lA + ((wr * 64 + m * 16 + fr) * 32 + fq * 8));
        #pragma unroll
        for (int n = 0; n < 4; ++n)
            bfr[n] = *(const bf16x8*)(lB + ((wc * 64 + n * 16 + fr) * 32 + fq * 8));
        #pragma unroll
        for (int m = 0; m < 4; ++m)
            #pragma unroll
            for (int n = 0; n < 4; ++n)
                acc[m][n] = __builtin_amdgcn_mfma_f32_16x16x32_bf16(af[m], bfr[n], acc[m][n], 0, 0, 0);
    }

    #pragma unroll
    for (int m = 0; m < 4; ++m) {
        const int rbase = bm * 128 + wr * 64 + m * 16 + fq * 4;
        #pragma unroll
        for (int n = 0; n < 4; ++n) {
            const int cn = bn * 128 + wc * 64 + n * 16 + fr;
            const float bb = bias[cn];
            #pragma unroll
            for (int j = 0; j < 4; ++j) {
                const int row = t0 + rbase + j;
                const float w = wts[(size_t)row * E_NUM + e];
                const float v = acc[m][n][j] + w * bb;   // Hc pre-scaled: only bias needs w
                float* p = out + (size_t)row * D_DIM + cn;
                if (MODE == 1) *p = v;
                else *p += v;
            }
        }
    }
}

extern "C" void kernel_launch(void* const* d_in, const int* in_sizes, int n_in,
                              void* d_out, int out_size, void* d_ws, size_t ws_size,
                              hipStream_t stream) {
    const float* x  = (const float*)d_in[0];
    const float* Wg = (const float*)d_in[1];
    const float* bg = (const float*)d_in[2];
    const float* W1 = (const float*)d_in[3];
    const float* b1 = (const float*)d_in[4];
    const float* W2 = (const float*)d_in[5];
    const float* b2 = (const float*)d_in[6];
    float* out = (float*)d_out;
    char* ws = (char*)d_ws;

    const size_t off_w  = 0;                                          // gate weights: 256 KiB
    const size_t off_x  = 262144;                                     // Xbf16: 16 MiB
    const size_t off_w1 = off_x + (size_t)T_TOK * D_DIM * 2;          // W1T bf16 [E][H][D]: 64 MiB
    const size_t off_w2 = off_w1 + (size_t)E_NUM * D_DIM * H_DIM * 2; // W2T bf16 [E][D][H]: 64 MiB
    const size_t off_h  = off_w2 + (size_t)E_NUM * D_DIM * H_DIM * 2; // Hc bf16 [TC][H]
    const size_t min_h  = (size_t)256 * H_DIM * 2;

    if (ws_size < off_h + min_h) {
        sentinel_kernel<<<2048, 256, 0, stream>>>(out, (size_t)T_TOK * D_DIM);
        return;
    }
    size_t avail = ws_size - off_h;

    float* wgt = (float*)(ws + off_w);
    unsigned short* Xb  = (unsigned short*)(ws + off_x);
    unsigned short* W1T = (unsigned short*)(ws + off_w1);
    unsigned short* W2T = (unsigned short*)(ws + off_w2);
    unsigned short* Hc  = (unsigned short*)(ws + off_h);

    gate_cvt_kernel<<<T_TOK / 4, 256, 0, stream>>>(x, Wg, bg, wgt, Xb);
    transpose_cvt<<<dim3(H_DIM / 64, D_DIM / 64, E_NUM), 256, 0, stream>>>(W1, W1T, D_DIM, H_DIM);
    transpose_cvt<<<dim3(D_DIM / 64, H_DIM / 64, E_NUM), 256, 0, stream>>>(W2, W2T, H_DIM, D_DIM);

    // per-expert Hc chunk of TC tokens (multiple of 256), L3-resident between gemm1 and gemm2
    size_t tc = avail / ((size_t)H_DIM * 2);
    tc = (tc / 256) * 256;
    if (tc > T_TOK) tc = T_TOK;
    const int TC = (int)tc;

    for (int t0 = 0; t0 < T_TOK; t0 += TC) {
        int cs = (T_TOK - t0 < TC) ? (T_TOK - t0) : TC;
        const int nbm1 = cs / 256;   // gemm1 256^2 tiles
        const int nbm2 = cs / 128;   // gemm2 128^2 tiles
        for (int e = 0; e < E_NUM; ++e) {
            gemm1_8ph<<<nbm1 * (H_DIM / 256), 512, 0, stream>>>(
                Xb + (size_t)t0 * D_DIM, W1T, Hc, b1, wgt, t0, e, nbm1);
            if (e == 0)
                gemm2_sep<1><<<nbm2 * (D_DIM / 128), 256, 0, stream>>>(
                    Hc, W2T + (size_t)e * D_DIM * H_DIM, out,
                    b2 + (size_t)e * D_DIM, wgt, t0, e, nbm2);
            else
                gemm2_sep<2><<<nbm2 * (D_DIM / 128), 256, 0, stream>>>(
                    Hc, W2T + (size_t)e * D_DIM * H_DIM, out,
                    b2 + (size_t)e * D_DIM, wgt, t0, e, nbm2);
        }
    }
}

// Round 7
// 1494.624 us; speedup vs baseline: 1.5977x; 1.0697x over previous
//
#include <hip/hip_runtime.h>
#include <hip/hip_bf16.h>

#define T_TOK 8192
#define D_DIM 1024
#define H_DIM 4096
#define E_NUM 8

typedef short bf16x8 __attribute__((ext_vector_type(8)));
typedef float f32x4 __attribute__((ext_vector_type(4)));

__device__ __forceinline__ unsigned short f2bf(float f) {
    union { float f; unsigned int u; } v; v.f = f;
    unsigned int u = v.u;
    u = u + 0x7FFFu + ((u >> 16) & 1u);   // round-to-nearest-even
    return (unsigned short)(u >> 16);
}

__device__ __forceinline__ void gload_lds16(const void* g, void* l) {
    __builtin_amdgcn_global_load_lds(
        (const __attribute__((address_space(1))) unsigned int*)g,
        (__attribute__((address_space(3))) unsigned int*)l,
        16, 0, 0);
}

// phase fences (rule 18 + pinned raw barrier)
#define SBAR() { __builtin_amdgcn_sched_barrier(0); __builtin_amdgcn_s_barrier(); __builtin_amdgcn_sched_barrier(0); }
#define LGKM0() { asm volatile("s_waitcnt lgkmcnt(0)" ::: "memory"); __builtin_amdgcn_sched_barrier(0); }
#define VMC4() { asm volatile("s_waitcnt vmcnt(4)" ::: "memory"); __builtin_amdgcn_sched_barrier(0); }
#define VMC6() { asm volatile("s_waitcnt vmcnt(6)" ::: "memory"); __builtin_amdgcn_sched_barrier(0); }
#define VMC0() { asm volatile("s_waitcnt vmcnt(0)" ::: "memory"); __builtin_amdgcn_sched_barrier(0); }

// XCD-chunked bijective swizzle + 8x4 supertile (T1, m157/m204)
__device__ __forceinline__ void swz_bmbn(int lin, int nbm, int nbn, int& bm, int& bn) {
    const int nwg = nbm * nbn;
    int wgid = ((nwg & 7) == 0) ? ((lin & 7) * (nwg >> 3) + (lin >> 3)) : lin;
    if ((nbm & 7) == 0 && (nbn & 3) == 0) {
        const int per = nbn << 3;
        int stripe = wgid / per;
        int l = wgid - stripe * per;
        int g = l >> 5, r = l & 31;               // 32 = 8 bm x 4 bn
        bm = stripe * 8 + (r >> 2);
        bn = g * 4 + (r & 3);
    } else {
        bm = wgid / nbn;
        bn = wgid - bm * nbn;
    }
}

// ------- gating (fp64, mask-exact) + fused x->bf16 convert -------
__global__ void gate_cvt_kernel(const float* __restrict__ x, const float* __restrict__ Wg,
                                const float* __restrict__ bg, float* __restrict__ wout,
                                unsigned short* __restrict__ xb) {
    int wv = (int)((blockIdx.x * blockDim.x + threadIdx.x) >> 6);  // token id
    int lane = threadIdx.x & 63;
    if (wv >= T_TOK) return;
    const float* xr = x + (size_t)wv * D_DIM;
    unsigned short* xo = xb + (size_t)wv * D_DIM;
    double acc[E_NUM] = {0, 0, 0, 0, 0, 0, 0, 0};
    for (int i = 0; i < D_DIM / 64; ++i) {
        int d = i * 64 + lane;
        float xf = xr[d];
        xo[d] = f2bf(xf);
        double xv = (double)xf;
        const float* wr = Wg + (size_t)d * E_NUM;
        #pragma unroll
        for (int e = 0; e < E_NUM; ++e) acc[e] += xv * (double)wr[e];
    }
    #pragma unroll
    for (int e = 0; e < E_NUM; ++e) {
        double v = acc[e];
        for (int s = 32; s; s >>= 1) v += __shfl_down(v, s, 64);
        acc[e] = v;
    }
    if (lane == 0) {
        #pragma unroll
        for (int e = 0; e < E_NUM; ++e) {
            double z = acc[e] + (double)bg[e];
            float p = (float)(1.0 / (1.0 + exp(-z)));
            wout[(size_t)wv * E_NUM + e] = (p > 0.5f) ? p : 0.0f;
        }
    }
}

// ------- per-expert transpose+convert: in[e][R][C] fp32 -> out[e][C][R] bf16 -------
__global__ void transpose_cvt(const float* __restrict__ in, unsigned short* __restrict__ out,
                              int R, int C) {
    __shared__ unsigned short tile[64][65];
    int e = blockIdx.z;
    const float* src = in + (size_t)e * R * C;
    unsigned short* dst = out + (size_t)e * R * C;
    int c0 = blockIdx.x * 64, r0 = blockIdx.y * 64;
    int t = threadIdx.x;
    int cc = (t & 15) * 4;
    int rr = t >> 4;
    #pragma unroll
    for (int p = 0; p < 4; ++p) {
        int r = rr + p * 16;
        float4 v = *(const float4*)(src + (size_t)(r0 + r) * C + c0 + cc);
        tile[cc + 0][r] = f2bf(v.x);
        tile[cc + 1][r] = f2bf(v.y);
        tile[cc + 2][r] = f2bf(v.z);
        tile[cc + 3][r] = f2bf(v.w);
    }
    __syncthreads();
    int rr4 = (t & 15) * 4;
    int cw = t >> 4;
    #pragma unroll
    for (int p = 0; p < 4; ++p) {
        int c = cw + p * 16;
        ushort4 o;
        o.x = tile[c][rr4 + 0];
        o.y = tile[c][rr4 + 1];
        o.z = tile[c][rr4 + 2];
        o.w = tile[c][rr4 + 3];
        *(ushort4*)(dst + (size_t)(c0 + c) * R + r0 + rr4) = o;
    }
}

// ---------------- sentinel: workspace too small marker ----------------
__global__ void sentinel_kernel(float* out, size_t n) {
    size_t i = (size_t)blockIdx.x * blockDim.x + threadIdx.x;
    size_t st = (size_t)gridDim.x * blockDim.x;
    for (; i < n; i += st) out[i] = 12345.0f;
}

// =================== GEMM1, 256x256 tile, BK=64, 8-wave, 4-phase/K-tile ===================
__global__ __launch_bounds__(512, 2) void gemm1_8ph(
    const unsigned short* __restrict__ A,
    const unsigned short* __restrict__ W1T,
    unsigned short* __restrict__ Hc,
    const float* __restrict__ b1,
    const float* __restrict__ wgt,
    int t0, int e, int nbm)
{
    __shared__ __align__(16) unsigned short lA[2][16384];
    __shared__ __align__(16) unsigned short lB[2][16384];

    const int nbn = H_DIM / 256;   // 16
    int bm, bn;
    swz_bmbn(blockIdx.x, nbm, nbn, bm, bn);

    const int tid = threadIdx.x;
    const int lane = tid & 63, wid = tid >> 6;
    const int wr = wid >> 2;        // 0..1  (M half)
    const int wcn = wid & 3;        // 0..3  (N quarter)
    const int fr = lane & 15, fq = lane >> 4;

    const int srow = tid >> 3;                                    // 0..63
    const int scol = (((tid & 7) ^ (srow & 7)) << 3);             // element offset
    const unsigned short* Ab = A + (size_t)(bm * 256 + srow) * D_DIM + scol;
    const unsigned short* Bb = W1T + (size_t)e * H_DIM * D_DIM
                             + (size_t)(bn * 256 + srow) * D_DIM + scol;

    const int s0 = ((0 << 2) | fq) ^ (fr & 7);
    const int s1 = ((1 << 2) | fq) ^ (fr & 7);

    f32x4 acc[8][4];
    #pragma unroll
    for (int m = 0; m < 8; ++m)
        #pragma unroll
        for (int n = 0; n < 4; ++n)
            acc[m][n] = (f32x4){0.f, 0.f, 0.f, 0.f};

    bf16x8 a[4][2], b[4][2];

    auto stageA = [&](int bf, int hf, int kt) {
        const unsigned short* s = Ab + (size_t)(hf * 128) * D_DIM + kt * 64;
        gload_lds16(s,                      &lA[bf][hf * 8192 + tid * 8]);
        gload_lds16(s + (size_t)64 * D_DIM, &lA[bf][hf * 8192 + 4096 + tid * 8]);
    };
    auto stageB = [&](int bf, int hf, int kt) {
        const unsigned short* s = Bb + (size_t)(hf * 128) * D_DIM + kt * 64;
        gload_lds16(s,                      &lB[bf][hf * 8192 + tid * 8]);
        gload_lds16(s + (size_t)64 * D_DIM, &lB[bf][hf * 8192 + 4096 + tid * 8]);
    };

    stageB(0, 0, 0);
    stageA(0, 0, 0);
    stageA(0, 1, 0);
    stageB(0, 1, 0);
    stageB(1, 0, 1);
    stageA(1, 0, 1);
    VMC4();
    SBAR();

    int cur = 0;
    for (int t = 0; t < 16; ++t) {
        const int nxt = cur ^ 1;
        #pragma unroll
        for (int mm = 0; mm < 4; ++mm) {
            const int r = wr * 128 + mm * 16 + fr;
            a[mm][0] = *(const bf16x8*)&lA[cur][r * 64 + s0 * 8];
            a[mm][1] = *(const bf16x8*)&lA[cur][r * 64 + s1 * 8];
        }
        #pragma unroll
        for (int n = 0; n < 2; ++n) {
            const int r = wcn * 64 + n * 16 + fr;
            b[n][0] = *(const bf16x8*)&lB[cur][r * 64 + s0 * 8];
            b[n][1] = *(const bf16x8*)&lB[cur][r * 64 + s1 * 8];
        }
        if (t + 1 < 16) stageA(nxt, 1, t + 1);
        SBAR(); LGKM0();
        __builtin_amdgcn_s_setprio(1);
        #pragma unroll
        for (int kk = 0; kk < 2; ++kk)
            #pragma unroll
            for (int mm = 0; mm < 4; ++mm) {
                acc[mm][0] = __builtin_amdgcn_mfma_f32_16x16x32_bf16(a[mm][kk], b[0][kk], acc[mm][0], 0, 0, 0);
                acc[mm][1] = __builtin_amdgcn_mfma_f32_16x16x32_bf16(a[mm][kk], b[1][kk], acc[mm][1], 0, 0, 0);
            }
        __builtin_amdgcn_s_setprio(0);
        SBAR();
        #pragma unroll
        for (int n = 2; n < 4; ++n) {
            const int r = wcn * 64 + n * 16 + fr;
            b[n][0] = *(const bf16x8*)&lB[cur][r * 64 + s0 * 8];
            b[n][1] = *(const bf16x8*)&lB[cur][r * 64 + s1 * 8];
        }
        if (t + 1 < 16) stageB(nxt, 1, t + 1);
        SBAR(); LGKM0();
        __builtin_amdgcn_s_setprio(1);
        #pragma unroll
        for (int kk = 0; kk < 2; ++kk)
            #pragma unroll
            for (int mm = 0; mm < 4; ++mm) {
                acc[mm][2] = __builtin_amdgcn_mfma_f32_16x16x32_bf16(a[mm][kk], b[2][kk], acc[mm][2], 0, 0, 0);
                acc[mm][3] = __builtin_amdgcn_mfma_f32_16x16x32_bf16(a[mm][kk], b[3][kk], acc[mm][3], 0, 0, 0);
            }
        __builtin_amdgcn_s_setprio(0);
        SBAR();
        #pragma unroll
        for (int mm = 0; mm < 4; ++mm) {
            const int r = wr * 128 + (mm + 4) * 16 + fr;
            a[mm][0] = *(const bf16x8*)&lA[cur][r * 64 + s0 * 8];
            a[mm][1] = *(const bf16x8*)&lA[cur][r * 64 + s1 * 8];
        }
        if (t + 2 < 16) stageB(cur, 0, t + 2);
        SBAR(); LGKM0();
        __builtin_amdgcn_s_setprio(1);
        #pragma unroll
        for (int kk = 0; kk < 2; ++kk)
            #pragma unroll
            for (int mm = 0; mm < 4; ++mm) {
                acc[mm + 4][0] = __builtin_amdgcn_mfma_f32_16x16x32_bf16(a[mm][kk], b[0][kk], acc[mm + 4][0], 0, 0, 0);
                acc[mm + 4][1] = __builtin_amdgcn_mfma_f32_16x16x32_bf16(a[mm][kk], b[1][kk], acc[mm + 4][1], 0, 0, 0);
            }
        __builtin_amdgcn_s_setprio(0);
        SBAR();
        if (t + 2 < 16) stageA(cur, 0, t + 2);
        if (t < 14) { VMC4(); } else { VMC0(); }
        SBAR(); LGKM0();
        __builtin_amdgcn_s_setprio(1);
        #pragma unroll
        for (int kk = 0; kk < 2; ++kk)
            #pragma unroll
            for (int mm = 0; mm < 4; ++mm) {
                acc[mm + 4][2] = __builtin_amdgcn_mfma_f32_16x16x32_bf16(a[mm][kk], b[2][kk], acc[mm + 4][2], 0, 0, 0);
                acc[mm + 4][3] = __builtin_amdgcn_mfma_f32_16x16x32_bf16(a[mm][kk], b[3][kk], acc[mm + 4][3], 0, 0, 0);
            }
        __builtin_amdgcn_s_setprio(0);
        SBAR();
        cur = nxt;
    }

    #pragma unroll
    for (int m = 0; m < 8; ++m) {
        const int rbase = bm * 256 + wr * 128 + m * 16 + fq * 4;
        #pragma unroll
        for (int n = 0; n < 4; ++n) {
            const int cn = bn * 256 + wcn * 64 + n * 16 + fr;
            const float bb = b1[(size_t)e * H_DIM + cn];
            #pragma unroll
            for (int j = 0; j < 4; ++j) {
                const int r = rbase + j;
                const float w = wgt[(size_t)(t0 + r) * E_NUM + e];
                float v = fmaxf(acc[m][n][j] + bb, 0.0f) * w;
                Hc[(size_t)r * H_DIM + cn] = f2bf(v);
            }
        }
    }
}

// ======== GEMM2, 256x128 tile, BK=64, 8-wave, 3-buffer depth-2, 2-phase/K-tile ========
// A = Hc [TC][H] (pre-scaled by gate weight), B = W2T[e] [D][H]. NT = 4096/64 = 64.
// MODE 1: out = acc + w*b2 ; MODE 2: out += acc + w*b2
template<int MODE>
__global__ __launch_bounds__(512, 2) void gemm2_8ph(
    const unsigned short* __restrict__ A,
    const unsigned short* __restrict__ B,
    float* __restrict__ out,
    const float* __restrict__ bias,
    const float* __restrict__ wts,
    int t0, int e, int nbm)
{
    __shared__ __align__(16) unsigned short lA[3][16384];   // 256 x 64
    __shared__ __align__(16) unsigned short lB[3][8192];    // 128 x 64

    const int nbn = D_DIM / 128;   // 8
    int bm, bn;
    swz_bmbn(blockIdx.x, nbm, nbn, bm, bn);

    const int tid = threadIdx.x;
    const int lane = tid & 63, wid = tid >> 6;
    const int wr = wid >> 2;        // 0..1  (M half: 128 rows)
    const int wcn = wid & 3;        // 0..3  (N quarter: 32 cols)
    const int fr = lane & 15, fq = lane >> 4;

    const int srow = tid >> 3;                                    // 0..63
    const int scol = (((tid & 7) ^ (srow & 7)) << 3);
    const unsigned short* Ab = A + (size_t)(bm * 256 + srow) * H_DIM + scol;
    const unsigned short* Bb = B + (size_t)(bn * 128 + srow) * H_DIM + scol;

    const int s0 = ((0 << 2) | fq) ^ (fr & 7);
    const int s1 = ((1 << 2) | fq) ^ (fr & 7);

    f32x4 acc[8][2];
    #pragma unroll
    for (int m = 0; m < 8; ++m)
        #pragma unroll
        for (int n = 0; n < 2; ++n)
            acc[m][n] = (f32x4){0.f, 0.f, 0.f, 0.f};

    bf16x8 a[4][2], b[2][2];

    auto stageA = [&](int bf, int hf, int kt) {
        const unsigned short* s = Ab + (size_t)(hf * 128) * H_DIM + kt * 64;
        gload_lds16(s,                      &lA[bf][hf * 8192 + tid * 8]);
        gload_lds16(s + (size_t)64 * H_DIM, &lA[bf][hf * 8192 + 4096 + tid * 8]);
    };
    auto stageB = [&](int bf, int kt) {
        const unsigned short* s = Bb + kt * 64;
        gload_lds16(s,                      &lB[bf][tid * 8]);
        gload_lds16(s + (size_t)64 * H_DIM, &lB[bf][4096 + tid * 8]);
    };

    // prologue: tile0 -> buf0, tile1 -> buf1 (6 gloads each)
    stageA(0, 0, 0); stageA(0, 1, 0); stageB(0, 0);
    stageA(1, 0, 1); stageA(1, 1, 1); stageB(1, 1);
    VMC6();          // tile0 complete (<=6 outstanding = tile1's)
    SBAR();

    int bt = 0, bs = 2;
    const int NT = H_DIM / 64;     // 64
    for (int t = 0; t < NT; ++t) {
        // ---- ph0: read a_lo + b from buf bt; stage A1,B(t+2)->bs; MFMA mh0 ----
        #pragma unroll
        for (int mm = 0; mm < 4; ++mm) {
            const int r = wr * 128 + mm * 16 + fr;
            a[mm][0] = *(const bf16x8*)&lA[bt][r * 64 + s0 * 8];
            a[mm][1] = *(const bf16x8*)&lA[bt][r * 64 + s1 * 8];
        }
        #pragma unroll
        for (int n = 0; n < 2; ++n) {
            const int r = wcn * 32 + n * 16 + fr;
            b[n][0] = *(const bf16x8*)&lB[bt][r * 64 + s0 * 8];
            b[n][1] = *(const bf16x8*)&lB[bt][r * 64 + s1 * 8];
        }
        if (t + 2 < NT) { stageA(bs, 1, t + 2); stageB(bs, t + 2); }
        SBAR(); LGKM0();
        __builtin_amdgcn_s_setprio(1);
        #pragma unroll
        for (int kk = 0; kk < 2; ++kk)
            #pragma unroll
            for (int mm = 0; mm < 4; ++mm) {
                acc[mm][0] = __builtin_amdgcn_mfma_f32_16x16x32_bf16(a[mm][kk], b[0][kk], acc[mm][0], 0, 0, 0);
                acc[mm][1] = __builtin_amdgcn_mfma_f32_16x16x32_bf16(a[mm][kk], b[1][kk], acc[mm][1], 0, 0, 0);
            }
        __builtin_amdgcn_s_setprio(0);
        SBAR();
        // ---- ph1: read a_hi from bt; stage A0(t+2)->bs; counted vmcnt; MFMA mh1 ----
        #pragma unroll
        for (int mm = 0; mm < 4; ++mm) {
            const int r = wr * 128 + (mm + 4) * 16 + fr;
            a[mm][0] = *(const bf16x8*)&lA[bt][r * 64 + s0 * 8];
            a[mm][1] = *(const bf16x8*)&lA[bt][r * 64 + s1 * 8];
        }
        if (t + 2 < NT) { stageA(bs, 0, t + 2); VMC6(); } else { VMC0(); }
        SBAR(); LGKM0();
        __builtin_amdgcn_s_setprio(1);
        #pragma unroll
        for (int kk = 0; kk < 2; ++kk)
            #pragma unroll
            for (int mm = 0; mm < 4; ++mm) {
                acc[mm + 4][0] = __builtin_amdgcn_mfma_f32_16x16x32_bf16(a[mm][kk], b[0][kk], acc[mm + 4][0], 0, 0, 0);
                acc[mm + 4][1] = __builtin_amdgcn_mfma_f32_16x16x32_bf16(a[mm][kk], b[1][kk], acc[mm + 4][1], 0, 0, 0);
            }
        __builtin_amdgcn_s_setprio(0);
        SBAR();
        bt = (bt == 2) ? 0 : bt + 1;
        bs = (bs == 2) ? 0 : bs + 1;
    }

    #pragma unroll
    for (int m = 0; m < 8; ++m) {
        const int rbase = bm * 256 + wr * 128 + m * 16 + fq * 4;
        #pragma unroll
        for (int n = 0; n < 2; ++n) {
            const int cn = bn * 128 + wcn * 32 + n * 16 + fr;
            const float bb = bias[cn];
            #pragma unroll
            for (int j = 0; j < 4; ++j) {
                const int row = t0 + rbase + j;
                const float w = wts[(size_t)row * E_NUM + e];
                const float v = acc[m][n][j] + w * bb;   // Hc pre-scaled: only bias needs w
                float* p = out + (size_t)row * D_DIM + cn;
                if (MODE == 1) *p = v;
                else *p += v;
            }
        }
    }
}

extern "C" void kernel_launch(void* const* d_in, const int* in_sizes, int n_in,
                              void* d_out, int out_size, void* d_ws, size_t ws_size,
                              hipStream_t stream) {
    const float* x  = (const float*)d_in[0];
    const float* Wg = (const float*)d_in[1];
    const float* bg = (const float*)d_in[2];
    const float* W1 = (const float*)d_in[3];
    const float* b1 = (const float*)d_in[4];
    const float* W2 = (const float*)d_in[5];
    const float* b2 = (const float*)d_in[6];
    float* out = (float*)d_out;
    char* ws = (char*)d_ws;

    const size_t off_w  = 0;                                          // gate weights: 256 KiB
    const size_t off_x  = 262144;                                     // Xbf16: 16 MiB
    const size_t off_w1 = off_x + (size_t)T_TOK * D_DIM * 2;          // W1T bf16 [E][H][D]: 64 MiB
    const size_t off_w2 = off_w1 + (size_t)E_NUM * D_DIM * H_DIM * 2; // W2T bf16 [E][D][H]: 64 MiB
    const size_t off_h  = off_w2 + (size_t)E_NUM * D_DIM * H_DIM * 2; // Hc bf16 [TC][H]
    const size_t min_h  = (size_t)256 * H_DIM * 2;

    if (ws_size < off_h + min_h) {
        sentinel_kernel<<<2048, 256, 0, stream>>>(out, (size_t)T_TOK * D_DIM);
        return;
    }
    size_t avail = ws_size - off_h;

    float* wgt = (float*)(ws + off_w);
    unsigned short* Xb  = (unsigned short*)(ws + off_x);
    unsigned short* W1T = (unsigned short*)(ws + off_w1);
    unsigned short* W2T = (unsigned short*)(ws + off_w2);
    unsigned short* Hc  = (unsigned short*)(ws + off_h);

    gate_cvt_kernel<<<T_TOK / 4, 256, 0, stream>>>(x, Wg, bg, wgt, Xb);
    transpose_cvt<<<dim3(H_DIM / 64, D_DIM / 64, E_NUM), 256, 0, stream>>>(W1, W1T, D_DIM, H_DIM);
    transpose_cvt<<<dim3(D_DIM / 64, H_DIM / 64, E_NUM), 256, 0, stream>>>(W2, W2T, H_DIM, D_DIM);

    // per-expert Hc chunk of TC tokens (multiple of 256), L3-resident between gemm1 and gemm2
    size_t tc = avail / ((size_t)H_DIM * 2);
    tc = (tc / 256) * 256;
    if (tc > T_TOK) tc = T_TOK;
    const int TC = (int)tc;

    for (int t0 = 0; t0 < T_TOK; t0 += TC) {
        int cs = (T_TOK - t0 < TC) ? (T_TOK - t0) : TC;
        const int nbm = cs / 256;
        for (int e = 0; e < E_NUM; ++e) {
            gemm1_8ph<<<nbm * (H_DIM / 256), 512, 0, stream>>>(
                Xb + (size_t)t0 * D_DIM, W1T, Hc, b1, wgt, t0, e, nbm);
            if (e == 0)
                gemm2_8ph<1><<<nbm * (D_DIM / 128), 512, 0, stream>>>(
                    Hc, W2T + (size_t)e * D_DIM * H_DIM, out,
                    b2 + (size_t)e * D_DIM, wgt, t0, e, nbm);
            else
                gemm2_8ph<2><<<nbm * (D_DIM / 128), 512, 0, stream>>>(
                    Hc, W2T + (size_t)e * D_DIM * H_DIM, out,
                    b2 + (size_t)e * D_DIM, wgt, t0, e, nbm);
        }
    }
}

// Round 8
// 1458.004 us; speedup vs baseline: 1.6379x; 1.0251x over previous
//
#include <hip/hip_runtime.h>
#include <hip/hip_bf16.h>

#define T_TOK 8192
#define D_DIM 1024
#define H_DIM 4096
#define E_NUM 8

typedef short bf16x8 __attribute__((ext_vector_type(8)));
typedef float f32x4 __attribute__((ext_vector_type(4)));

__device__ __forceinline__ unsigned short f2bf(float f) {
    union { float f; unsigned int u; } v; v.f = f;
    unsigned int u = v.u;
    u = u + 0x7FFFu + ((u >> 16) & 1u);   // round-to-nearest-even
    return (unsigned short)(u >> 16);
}

__device__ __forceinline__ void gload_lds16(const void* g, void* l) {
    __builtin_amdgcn_global_load_lds(
        (const __attribute__((address_space(1))) unsigned int*)g,
        (__attribute__((address_space(3))) unsigned int*)l,
        16, 0, 0);
}

// phase fences (rule 18 + pinned raw barrier)
#define SBAR() { __builtin_amdgcn_sched_barrier(0); __builtin_amdgcn_s_barrier(); __builtin_amdgcn_sched_barrier(0); }
#define LGKM0() { asm volatile("s_waitcnt lgkmcnt(0)" ::: "memory"); __builtin_amdgcn_sched_barrier(0); }
#define VMC4() { asm volatile("s_waitcnt vmcnt(4)" ::: "memory"); __builtin_amdgcn_sched_barrier(0); }
#define VMC6() { asm volatile("s_waitcnt vmcnt(6)" ::: "memory"); __builtin_amdgcn_sched_barrier(0); }
#define VMC0() { asm volatile("s_waitcnt vmcnt(0)" ::: "memory"); __builtin_amdgcn_sched_barrier(0); }

// XCD-chunked bijective swizzle + 8x4 supertile (T1, m157/m204)
__device__ __forceinline__ void swz_bmbn(int lin, int nbm, int nbn, int& bm, int& bn) {
    const int nwg = nbm * nbn;
    int wgid = ((nwg & 7) == 0) ? ((lin & 7) * (nwg >> 3) + (lin >> 3)) : lin;
    if ((nbm & 7) == 0 && (nbn & 3) == 0) {
        const int per = nbn << 3;
        int stripe = wgid / per;
        int l = wgid - stripe * per;
        int g = l >> 5, r = l & 31;               // 32 = 8 bm x 4 bn
        bm = stripe * 8 + (r >> 2);
        bn = g * 4 + (r & 3);
    } else {
        bm = wgid / nbn;
        bn = wgid - bm * nbn;
    }
}

// ------- gating (fp64, mask-exact) + fused x->bf16 convert -------
__global__ void gate_cvt_kernel(const float* __restrict__ x, const float* __restrict__ Wg,
                                const float* __restrict__ bg, float* __restrict__ wout,
                                unsigned short* __restrict__ xb) {
    int wv = (int)((blockIdx.x * blockDim.x + threadIdx.x) >> 6);  // token id
    int lane = threadIdx.x & 63;
    if (wv >= T_TOK) return;
    const float* xr = x + (size_t)wv * D_DIM;
    unsigned short* xo = xb + (size_t)wv * D_DIM;
    double acc[E_NUM] = {0, 0, 0, 0, 0, 0, 0, 0};
    for (int i = 0; i < D_DIM / 64; ++i) {
        int d = i * 64 + lane;
        float xf = xr[d];
        xo[d] = f2bf(xf);
        double xv = (double)xf;
        const float* wr = Wg + (size_t)d * E_NUM;
        #pragma unroll
        for (int e = 0; e < E_NUM; ++e) acc[e] += xv * (double)wr[e];
    }
    #pragma unroll
    for (int e = 0; e < E_NUM; ++e) {
        double v = acc[e];
        for (int s = 32; s; s >>= 1) v += __shfl_down(v, s, 64);
        acc[e] = v;
    }
    if (lane == 0) {
        #pragma unroll
        for (int e = 0; e < E_NUM; ++e) {
            double z = acc[e] + (double)bg[e];
            float p = (float)(1.0 / (1.0 + exp(-z)));
            wout[(size_t)wv * E_NUM + e] = (p > 0.5f) ? p : 0.0f;
        }
    }
}

// ------- per-expert transpose+convert: in[e][R][C] fp32 -> out[e][C][R] bf16 -------
__global__ void transpose_cvt(const float* __restrict__ in, unsigned short* __restrict__ out,
                              int R, int C) {
    __shared__ unsigned short tile[64][65];
    int e = blockIdx.z;
    const float* src = in + (size_t)e * R * C;
    unsigned short* dst = out + (size_t)e * R * C;
    int c0 = blockIdx.x * 64, r0 = blockIdx.y * 64;
    int t = threadIdx.x;
    int cc = (t & 15) * 4;
    int rr = t >> 4;
    #pragma unroll
    for (int p = 0; p < 4; ++p) {
        int r = rr + p * 16;
        float4 v = *(const float4*)(src + (size_t)(r0 + r) * C + c0 + cc);
        tile[cc + 0][r] = f2bf(v.x);
        tile[cc + 1][r] = f2bf(v.y);
        tile[cc + 2][r] = f2bf(v.z);
        tile[cc + 3][r] = f2bf(v.w);
    }
    __syncthreads();
    int rr4 = (t & 15) * 4;
    int cw = t >> 4;
    #pragma unroll
    for (int p = 0; p < 4; ++p) {
        int c = cw + p * 16;
        ushort4 o;
        o.x = tile[c][rr4 + 0];
        o.y = tile[c][rr4 + 1];
        o.z = tile[c][rr4 + 2];
        o.w = tile[c][rr4 + 3];
        *(ushort4*)(dst + (size_t)(c0 + c) * R + r0 + rr4) = o;
    }
}

// ---------------- sentinel: workspace too small marker ----------------
__global__ void sentinel_kernel(float* out, size_t n) {
    size_t i = (size_t)blockIdx.x * blockDim.x + threadIdx.x;
    size_t st = (size_t)gridDim.x * blockDim.x;
    for (; i < n; i += st) out[i] = 12345.0f;
}

// =================== GEMM1, 256x256 tile, BK=64, 8-wave, 4-phase/K-tile ===================
__global__ __launch_bounds__(512, 2) void gemm1_8ph(
    const unsigned short* __restrict__ A,
    const unsigned short* __restrict__ W1T,
    unsigned short* __restrict__ Hc,
    const float* __restrict__ b1,
    const float* __restrict__ wgt,
    int t0, int e, int nbm)
{
    __shared__ __align__(16) unsigned short lA[2][16384];
    __shared__ __align__(16) unsigned short lB[2][16384];

    const int nbn = H_DIM / 256;   // 16
    int bm, bn;
    swz_bmbn(blockIdx.x, nbm, nbn, bm, bn);

    const int tid = threadIdx.x;
    const int lane = tid & 63, wid = tid >> 6;
    const int wr = wid >> 2;        // 0..1  (M half)
    const int wcn = wid & 3;        // 0..3  (N quarter)
    const int fr = lane & 15, fq = lane >> 4;

    const int srow = tid >> 3;                                    // 0..63
    const int scol = (((tid & 7) ^ (srow & 7)) << 3);             // element offset
    const unsigned short* Ab = A + (size_t)(bm * 256 + srow) * D_DIM + scol;
    const unsigned short* Bb = W1T + (size_t)e * H_DIM * D_DIM
                             + (size_t)(bn * 256 + srow) * D_DIM + scol;

    const int s0 = ((0 << 2) | fq) ^ (fr & 7);
    const int s1 = ((1 << 2) | fq) ^ (fr & 7);

    f32x4 acc[8][4];
    #pragma unroll
    for (int m = 0; m < 8; ++m)
        #pragma unroll
        for (int n = 0; n < 4; ++n)
            acc[m][n] = (f32x4){0.f, 0.f, 0.f, 0.f};

    bf16x8 a[4][2], b[4][2];

    auto stageA = [&](int bf, int hf, int kt) {
        const unsigned short* s = Ab + (size_t)(hf * 128) * D_DIM + kt * 64;
        gload_lds16(s,                      &lA[bf][hf * 8192 + tid * 8]);
        gload_lds16(s + (size_t)64 * D_DIM, &lA[bf][hf * 8192 + 4096 + tid * 8]);
    };
    auto stageB = [&](int bf, int hf, int kt) {
        const unsigned short* s = Bb + (size_t)(hf * 128) * D_DIM + kt * 64;
        gload_lds16(s,                      &lB[bf][hf * 8192 + tid * 8]);
        gload_lds16(s + (size_t)64 * D_DIM, &lB[bf][hf * 8192 + 4096 + tid * 8]);
    };

    stageB(0, 0, 0);
    stageA(0, 0, 0);
    stageA(0, 1, 0);
    stageB(0, 1, 0);
    stageB(1, 0, 1);
    stageA(1, 0, 1);
    VMC4();
    SBAR();

    int cur = 0;
    for (int t = 0; t < 16; ++t) {
        const int nxt = cur ^ 1;
        #pragma unroll
        for (int mm = 0; mm < 4; ++mm) {
            const int r = wr * 128 + mm * 16 + fr;
            a[mm][0] = *(const bf16x8*)&lA[cur][r * 64 + s0 * 8];
            a[mm][1] = *(const bf16x8*)&lA[cur][r * 64 + s1 * 8];
        }
        #pragma unroll
        for (int n = 0; n < 2; ++n) {
            const int r = wcn * 64 + n * 16 + fr;
            b[n][0] = *(const bf16x8*)&lB[cur][r * 64 + s0 * 8];
            b[n][1] = *(const bf16x8*)&lB[cur][r * 64 + s1 * 8];
        }
        if (t + 1 < 16) stageA(nxt, 1, t + 1);
        SBAR(); LGKM0();
        __builtin_amdgcn_s_setprio(1);
        #pragma unroll
        for (int kk = 0; kk < 2; ++kk)
            #pragma unroll
            for (int mm = 0; mm < 4; ++mm) {
                acc[mm][0] = __builtin_amdgcn_mfma_f32_16x16x32_bf16(a[mm][kk], b[0][kk], acc[mm][0], 0, 0, 0);
                acc[mm][1] = __builtin_amdgcn_mfma_f32_16x16x32_bf16(a[mm][kk], b[1][kk], acc[mm][1], 0, 0, 0);
            }
        __builtin_amdgcn_s_setprio(0);
        SBAR();
        #pragma unroll
        for (int n = 2; n < 4; ++n) {
            const int r = wcn * 64 + n * 16 + fr;
            b[n][0] = *(const bf16x8*)&lB[cur][r * 64 + s0 * 8];
            b[n][1] = *(const bf16x8*)&lB[cur][r * 64 + s1 * 8];
        }
        if (t + 1 < 16) stageB(nxt, 1, t + 1);
        SBAR(); LGKM0();
        __builtin_amdgcn_s_setprio(1);
        #pragma unroll
        for (int kk = 0; kk < 2; ++kk)
            #pragma unroll
            for (int mm = 0; mm < 4; ++mm) {
                acc[mm][2] = __builtin_amdgcn_mfma_f32_16x16x32_bf16(a[mm][kk], b[2][kk], acc[mm][2], 0, 0, 0);
                acc[mm][3] = __builtin_amdgcn_mfma_f32_16x16x32_bf16(a[mm][kk], b[3][kk], acc[mm][3], 0, 0, 0);
            }
        __builtin_amdgcn_s_setprio(0);
        SBAR();
        #pragma unroll
        for (int mm = 0; mm < 4; ++mm) {
            const int r = wr * 128 + (mm + 4) * 16 + fr;
            a[mm][0] = *(const bf16x8*)&lA[cur][r * 64 + s0 * 8];
            a[mm][1] = *(const bf16x8*)&lA[cur][r * 64 + s1 * 8];
        }
        if (t + 2 < 16) stageB(cur, 0, t + 2);
        SBAR(); LGKM0();
        __builtin_amdgcn_s_setprio(1);
        #pragma unroll
        for (int kk = 0; kk < 2; ++kk)
            #pragma unroll
            for (int mm = 0; mm < 4; ++mm) {
                acc[mm + 4][0] = __builtin_amdgcn_mfma_f32_16x16x32_bf16(a[mm][kk], b[0][kk], acc[mm + 4][0], 0, 0, 0);
                acc[mm + 4][1] = __builtin_amdgcn_mfma_f32_16x16x32_bf16(a[mm][kk], b[1][kk], acc[mm + 4][1], 0, 0, 0);
            }
        __builtin_amdgcn_s_setprio(0);
        SBAR();
        if (t + 2 < 16) stageA(cur, 0, t + 2);
        if (t < 14) { VMC4(); } else { VMC0(); }
        SBAR(); LGKM0();
        __builtin_amdgcn_s_setprio(1);
        #pragma unroll
        for (int kk = 0; kk < 2; ++kk)
            #pragma unroll
            for (int mm = 0; mm < 4; ++mm) {
                acc[mm + 4][2] = __builtin_amdgcn_mfma_f32_16x16x32_bf16(a[mm][kk], b[2][kk], acc[mm + 4][2], 0, 0, 0);
                acc[mm + 4][3] = __builtin_amdgcn_mfma_f32_16x16x32_bf16(a[mm][kk], b[3][kk], acc[mm + 4][3], 0, 0, 0);
            }
        __builtin_amdgcn_s_setprio(0);
        SBAR();
        cur = nxt;
    }

    #pragma unroll
    for (int m = 0; m < 8; ++m) {
        const int rbase = bm * 256 + wr * 128 + m * 16 + fq * 4;
        #pragma unroll
        for (int n = 0; n < 4; ++n) {
            const int cn = bn * 256 + wcn * 64 + n * 16 + fr;
            const float bb = b1[(size_t)e * H_DIM + cn];
            #pragma unroll
            for (int j = 0; j < 4; ++j) {
                const int r = rbase + j;
                const float w = wgt[(size_t)(t0 + r) * E_NUM + e];
                float v = fmaxf(acc[m][n][j] + bb, 0.0f) * w;
                Hc[(size_t)r * H_DIM + cn] = f2bf(v);
            }
        }
    }
}

// ======== GEMM2, 256x128 tile, BK=64, 8-wave 4Mx2N (wave=64x64), 3-buffer depth-2 ========
// A = Hc [TC][H] (pre-scaled by gate weight), B = W2T[e] [D][H]. NT = 4096/64 = 64.
// MODE 1: out = acc + w*b2 ; MODE 2: out += acc + w*b2
template<int MODE>
__global__ __launch_bounds__(512, 2) void gemm2_8ph(
    const unsigned short* __restrict__ A,
    const unsigned short* __restrict__ B,
    float* __restrict__ out,
    const float* __restrict__ bias,
    const float* __restrict__ wts,
    int t0, int e, int nbm)
{
    __shared__ __align__(16) unsigned short lA[3][16384];   // 256 x 64
    __shared__ __align__(16) unsigned short lB[3][8192];    // 128 x 64

    const int nbn = D_DIM / 128;   // 8
    int bm, bn;
    swz_bmbn(blockIdx.x, nbm, nbn, bm, bn);

    const int tid = threadIdx.x;
    const int lane = tid & 63, wid = tid >> 6;
    const int wr = wid >> 1;        // 0..3  (M quarter: 64 rows)
    const int wcn = wid & 1;        // 0..1  (N half: 64 cols)
    const int fr = lane & 15, fq = lane >> 4;

    const int srow = tid >> 3;                                    // 0..63
    const int scol = (((tid & 7) ^ (srow & 7)) << 3);
    const unsigned short* Ab = A + (size_t)(bm * 256 + srow) * H_DIM + scol;
    const unsigned short* Bb = B + (size_t)(bn * 128 + srow) * H_DIM + scol;

    const int s0 = ((0 << 2) | fq) ^ (fr & 7);
    const int s1 = ((1 << 2) | fq) ^ (fr & 7);

    f32x4 acc[4][4];
    #pragma unroll
    for (int m = 0; m < 4; ++m)
        #pragma unroll
        for (int n = 0; n < 4; ++n)
            acc[m][n] = (f32x4){0.f, 0.f, 0.f, 0.f};

    bf16x8 a[4][2], b[4][2];

    auto stageA = [&](int bf, int hf, int kt) {
        const unsigned short* s = Ab + (size_t)(hf * 128) * H_DIM + kt * 64;
        gload_lds16(s,                      &lA[bf][hf * 8192 + tid * 8]);
        gload_lds16(s + (size_t)64 * H_DIM, &lA[bf][hf * 8192 + 4096 + tid * 8]);
    };
    auto stageB = [&](int bf, int kt) {
        const unsigned short* s = Bb + kt * 64;
        gload_lds16(s,                      &lB[bf][tid * 8]);
        gload_lds16(s + (size_t)64 * H_DIM, &lB[bf][4096 + tid * 8]);
    };

    // prologue: tile0 -> buf0, tile1 -> buf1 (6 gloads each)
    stageA(0, 0, 0); stageA(0, 1, 0); stageB(0, 0);
    stageA(1, 0, 1); stageA(1, 1, 1); stageB(1, 1);
    VMC6();          // tile0 complete (<=6 outstanding = tile1's)
    SBAR();

    int bt = 0, bs = 2;
    const int NT = H_DIM / 64;     // 64
    for (int t = 0; t < NT; ++t) {
        // ---- ph0: read a (all 4 M-frags) + b[0..1]; stage A1,B(t+2)->bs; MFMA n0,n1 ----
        #pragma unroll
        for (int mm = 0; mm < 4; ++mm) {
            const int r = wr * 64 + mm * 16 + fr;
            a[mm][0] = *(const bf16x8*)&lA[bt][r * 64 + s0 * 8];
            a[mm][1] = *(const bf16x8*)&lA[bt][r * 64 + s1 * 8];
        }
        #pragma unroll
        for (int n = 0; n < 2; ++n) {
            const int r = wcn * 64 + n * 16 + fr;
            b[n][0] = *(const bf16x8*)&lB[bt][r * 64 + s0 * 8];
            b[n][1] = *(const bf16x8*)&lB[bt][r * 64 + s1 * 8];
        }
        if (t + 2 < NT) { stageA(bs, 1, t + 2); stageB(bs, t + 2); }
        SBAR(); LGKM0();
        __builtin_amdgcn_s_setprio(1);
        #pragma unroll
        for (int kk = 0; kk < 2; ++kk)
            #pragma unroll
            for (int mm = 0; mm < 4; ++mm) {
                acc[mm][0] = __builtin_amdgcn_mfma_f32_16x16x32_bf16(a[mm][kk], b[0][kk], acc[mm][0], 0, 0, 0);
                acc[mm][1] = __builtin_amdgcn_mfma_f32_16x16x32_bf16(a[mm][kk], b[1][kk], acc[mm][1], 0, 0, 0);
            }
        __builtin_amdgcn_s_setprio(0);
        SBAR();
        // ---- ph1: read b[2..3]; stage A0(t+2)->bs; counted vmcnt; MFMA n2,n3 ----
        #pragma unroll
        for (int n = 2; n < 4; ++n) {
            const int r = wcn * 64 + n * 16 + fr;
            b[n][0] = *(const bf16x8*)&lB[bt][r * 64 + s0 * 8];
            b[n][1] = *(const bf16x8*)&lB[bt][r * 64 + s1 * 8];
        }
        if (t + 2 < NT) { stageA(bs, 0, t + 2); VMC6(); } else { VMC0(); }
        SBAR(); LGKM0();
        __builtin_amdgcn_s_setprio(1);
        #pragma unroll
        for (int kk = 0; kk < 2; ++kk)
            #pragma unroll
            for (int mm = 0; mm < 4; ++mm) {
                acc[mm][2] = __builtin_amdgcn_mfma_f32_16x16x32_bf16(a[mm][kk], b[2][kk], acc[mm][2], 0, 0, 0);
                acc[mm][3] = __builtin_amdgcn_mfma_f32_16x16x32_bf16(a[mm][kk], b[3][kk], acc[mm][3], 0, 0, 0);
            }
        __builtin_amdgcn_s_setprio(0);
        SBAR();
        bt = (bt == 2) ? 0 : bt + 1;
        bs = (bs == 2) ? 0 : bs + 1;
    }

    #pragma unroll
    for (int m = 0; m < 4; ++m) {
        const int rbase = bm * 256 + wr * 64 + m * 16 + fq * 4;
        #pragma unroll
        for (int n = 0; n < 4; ++n) {
            const int cn = bn * 128 + wcn * 64 + n * 16 + fr;
            const float bb = bias[cn];
            #pragma unroll
            for (int j = 0; j < 4; ++j) {
                const int row = t0 + rbase + j;
                const float w = wts[(size_t)row * E_NUM + e];
                const float v = acc[m][n][j] + w * bb;   // Hc pre-scaled: only bias needs w
                float* p = out + (size_t)row * D_DIM + cn;
                if (MODE == 1) *p = v;
                else *p += v;
            }
        }
    }
}

extern "C" void kernel_launch(void* const* d_in, const int* in_sizes, int n_in,
                              void* d_out, int out_size, void* d_ws, size_t ws_size,
                              hipStream_t stream) {
    const float* x  = (const float*)d_in[0];
    const float* Wg = (const float*)d_in[1];
    const float* bg = (const float*)d_in[2];
    const float* W1 = (const float*)d_in[3];
    const float* b1 = (const float*)d_in[4];
    const float* W2 = (const float*)d_in[5];
    const float* b2 = (const float*)d_in[6];
    float* out = (float*)d_out;
    char* ws = (char*)d_ws;

    const size_t off_w  = 0;                                          // gate weights: 256 KiB
    const size_t off_x  = 262144;                                     // Xbf16: 16 MiB
    const size_t off_w1 = off_x + (size_t)T_TOK * D_DIM * 2;          // W1T bf16 [E][H][D]: 64 MiB
    const size_t off_w2 = off_w1 + (size_t)E_NUM * D_DIM * H_DIM * 2; // W2T bf16 [E][D][H]: 64 MiB
    const size_t off_h  = off_w2 + (size_t)E_NUM * D_DIM * H_DIM * 2; // Hc bf16 [TC][H]
    const size_t min_h  = (size_t)256 * H_DIM * 2;

    if (ws_size < off_h + min_h) {
        sentinel_kernel<<<2048, 256, 0, stream>>>(out, (size_t)T_TOK * D_DIM);
        return;
    }
    size_t avail = ws_size - off_h;

    float* wgt = (float*)(ws + off_w);
    unsigned short* Xb  = (unsigned short*)(ws + off_x);
    unsigned short* W1T = (unsigned short*)(ws + off_w1);
    unsigned short* W2T = (unsigned short*)(ws + off_w2);
    unsigned short* Hc  = (unsigned short*)(ws + off_h);

    gate_cvt_kernel<<<T_TOK / 4, 256, 0, stream>>>(x, Wg, bg, wgt, Xb);
    transpose_cvt<<<dim3(H_DIM / 64, D_DIM / 64, E_NUM), 256, 0, stream>>>(W1, W1T, D_DIM, H_DIM);
    transpose_cvt<<<dim3(D_DIM / 64, H_DIM / 64, E_NUM), 256, 0, stream>>>(W2, W2T, H_DIM, D_DIM);

    // per-expert Hc chunk of TC tokens (multiple of 256), L3-resident between gemm1 and gemm2
    size_t tc = avail / ((size_t)H_DIM * 2);
    tc = (tc / 256) * 256;
    if (tc > T_TOK) tc = T_TOK;
    const int TC = (int)tc;

    for (int t0 = 0; t0 < T_TOK; t0 += TC) {
        int cs = (T_TOK - t0 < TC) ? (T_TOK - t0) : TC;
        const int nbm = cs / 256;
        for (int e = 0; e < E_NUM; ++e) {
            gemm1_8ph<<<nbm * (H_DIM / 256), 512, 0, stream>>>(
                Xb + (size_t)t0 * D_DIM, W1T, Hc, b1, wgt, t0, e, nbm);
            if (e == 0)
                gemm2_8ph<1><<<nbm * (D_DIM / 128), 512, 0, stream>>>(
                    Hc, W2T + (size_t)e * D_DIM * H_DIM, out,
                    b2 + (size_t)e * D_DIM, wgt, t0, e, nbm);
            else
                gemm2_8ph<2><<<nbm * (D_DIM / 128), 512, 0, stream>>>(
                    Hc, W2T + (size_t)e * D_DIM * H_DIM, out,
                    b2 + (size_t)e * D_DIM, wgt, t0, e, nbm);
        }
    }
}